// Round 5
// baseline (586.431 us; speedup 1.0000x reference)
//
#include <hip/hip_runtime.h>

typedef __attribute__((ext_vector_type(4))) float  f32x4;
typedef __attribute__((ext_vector_type(8))) short  s16x8;
typedef __attribute__((ext_vector_type(4))) short  s16x4;

static __device__ __forceinline__ short f2bf(float f) {
    unsigned int x = __builtin_bit_cast(unsigned int, f);
    x += 0x7fffu + ((x >> 16) & 1u);
    return (short)(x >> 16);
}

// ---------------- prep kernels ----------------
__global__ __launch_bounds__(256) void castall(
    const float* __restrict__ emb, const float* __restrict__ ipw,
    const float* __restrict__ outw, const float* __restrict__ linw,
    short* __restrict__ de, short* __restrict__ di,
    short* __restrict__ dg, short* __restrict__ dl)
{
    int q = blockIdx.x * 256 + threadIdx.x;   // quad index, total 294912
    const float* s; short* d; int o;
    if (q < 131072)      { s = emb;  d = de; o = q; }
    else if (q < 229376) { s = ipw;  d = di; o = q - 131072; }
    else if (q < 262144) { s = outw; d = dg; o = q - 229376; }
    else                 { s = linw; d = dl; o = q - 262144; }
    f32x4 v = *(const f32x4*)(s + (size_t)o * 4);
    s16x4 r;
    #pragma unroll
    for (int j = 0; j < 4; ++j) r[j] = f2bf(v[j]);
    *(s16x4*)(d + (size_t)o * 4) = r;
}

// WT[c][cin] = W[cin][c], 256x256
__global__ __launch_bounds__(256) void tcast256(const float* __restrict__ in,
                                                short* __restrict__ out) {
    out[blockIdx.x * 256 + threadIdx.x] = f2bf(in[threadIdx.x * 256 + blockIdx.x]);
}

// ============ barrier-free GEMM: C = A * B^T (+bias), K=256 fixed ============
// B (N x 256, bf16 row-major) slice staged ONCE in LDS (XOR-swizzled rows).
// A fragments stream global->registers (native MFMA frag pattern). No barriers
// in the K loop -> waves run free; loads hoisted across MFMAs by compiler.
template<bool AF32, bool OF32, bool OB16>
__global__ __launch_bounds__(256) void gemm_rb(
    const void* __restrict__ Av, const short* __restrict__ Bm,
    const float* __restrict__ bias,
    float* __restrict__ Cf, short* __restrict__ Cb,
    int M, int N)
{
    __shared__ short lsB[128 * 256];   // 64 KB
    const int tid = threadIdx.x;
    const int m0 = blockIdx.x * 128;
    const int n0 = blockIdx.y * 128;
    const int lane = tid & 63;
    const int w = tid >> 6;
    const int wmi = w >> 1, wni = w & 1;
    const int lr = lane & 15, ko = lane >> 4;

    // stage B slice once: 2 threads/row, 16x 16B chunks each, swizzled
    {
        const int r0 = tid >> 1, hb = tid & 1;
        const short* Bp = Bm + (size_t)(n0 + r0) * 256 + hb * 128;
        const int sw = (r0 & 7) << 4;
        char* dst = (char*)(lsB + r0 * 256);
        #pragma unroll
        for (int i = 0; i < 16; ++i) {
            int cb = (hb * 16 + i) * 16;
            *(s16x8*)(dst + (cb ^ sw)) = *(const s16x8*)(Bp + i * 8);
        }
    }
    __syncthreads();

    const int swr = (lr & 7) << 4;
    f32x4 acc[4][4] = {};
    #pragma unroll
    for (int ks = 0; ks < 8; ++ks) {
        const int k0 = ks * 32;
        s16x8 af[4];
        #pragma unroll
        for (int mt = 0; mt < 4; ++mt) {
            const int rowA = m0 + wmi * 64 + mt * 16 + lr;
            if constexpr (AF32) {
                const float* Ap = (const float*)Av + (size_t)rowA * 256 + k0 + ko * 8;
                f32x4 x0 = *(const f32x4*)Ap;
                f32x4 x1 = *(const f32x4*)(Ap + 4);
                #pragma unroll
                for (int j = 0; j < 4; ++j) { af[mt][j] = f2bf(x0[j]); af[mt][4 + j] = f2bf(x1[j]); }
            } else {
                const short* Ap = (const short*)Av + (size_t)rowA * 256 + k0 + ko * 8;
                af[mt] = *(const s16x8*)Ap;
            }
        }
        s16x8 bf[4];
        #pragma unroll
        for (int nt = 0; nt < 4; ++nt) {
            const int nrow = wni * 64 + nt * 16 + lr;
            bf[nt] = *(const s16x8*)((const char*)(lsB + nrow * 256) + ((k0 * 2 + ko * 16) ^ swr));
        }
        #pragma unroll
        for (int mt = 0; mt < 4; ++mt)
            #pragma unroll
            for (int nt = 0; nt < 4; ++nt)
                acc[mt][nt] = __builtin_amdgcn_mfma_f32_16x16x32_bf16(af[mt], bf[nt], acc[mt][nt], 0, 0, 0);
    }
    const int cr = ko * 4, cc = lr;
    #pragma unroll
    for (int mt = 0; mt < 4; ++mt)
    #pragma unroll
    for (int nt = 0; nt < 4; ++nt) {
        const int col = n0 + wni * 64 + nt * 16 + cc;
        const float bv = bias ? bias[col] : 0.f;
        #pragma unroll
        for (int j = 0; j < 4; ++j) {
            const int row = m0 + wmi * 64 + mt * 16 + cr + j;
            float v = acc[mt][nt][j] + bv;
            size_t idx = (size_t)row * N + col;
            if constexpr (OF32) Cf[idx] = v;
            if constexpr (OB16) Cb[idx] = f2bf(v);
        }
    }
}

// ---------------- scores + softmax over latent k (barrier-free K loop) -------
// A-operand = emb[g] (128x256) staged once in LDS; B-operand = x4 streamed to
// registers. Softmax red-arrays overlay the LDS after a post-loop barrier.
__global__ __launch_bounds__(256) void scores_softmax(
    const short* __restrict__ embb, const short* __restrict__ x4b,
    float* __restrict__ attnF, short* __restrict__ attnB)
{
    __shared__ short lsA[128 * 256];   // 64 KB (emb); overlaid by red arrays
    float* redm = (float*)lsA;         // 256 floats
    float* reds = redm + 256;          // 256 floats
    const int tid = threadIdx.x;
    const int z = blockIdx.y;
    const int g = z & 15;
    const int t0 = blockIdx.x * 128;
    const short* A = embb + (size_t)g * 32768;
    const short* B = x4b + (size_t)z * 262144 + (size_t)t0 * 256;
    const int lane = tid & 63;
    const int w = tid >> 6;
    const int wmi = w >> 1, wni = w & 1;
    const int lr = lane & 15, ko = lane >> 4;

    {
        const int r0 = tid >> 1, hb = tid & 1;
        const short* Ap = A + (size_t)r0 * 256 + hb * 128;
        const int sw = (r0 & 7) << 4;
        char* dst = (char*)(lsA + r0 * 256);
        #pragma unroll
        for (int i = 0; i < 16; ++i) {
            int cb = (hb * 16 + i) * 16;
            *(s16x8*)(dst + (cb ^ sw)) = *(const s16x8*)(Ap + i * 8);
        }
    }
    __syncthreads();

    const int swr = (lr & 7) << 4;
    f32x4 acc[4][4] = {};
    #pragma unroll
    for (int ks = 0; ks < 8; ++ks) {
        const int k0 = ks * 32;
        s16x8 af[4];
        #pragma unroll
        for (int mt = 0; mt < 4; ++mt) {
            const int krow = wmi * 64 + mt * 16 + lr;
            af[mt] = *(const s16x8*)((const char*)(lsA + krow * 256) + ((k0 * 2 + ko * 16) ^ swr));
        }
        s16x8 bf[4];
        #pragma unroll
        for (int nt = 0; nt < 4; ++nt) {
            const int trow = wni * 64 + nt * 16 + lr;
            bf[nt] = *(const s16x8*)(B + (size_t)trow * 256 + k0 + ko * 8);
        }
        #pragma unroll
        for (int mt = 0; mt < 4; ++mt)
            #pragma unroll
            for (int nt = 0; nt < 4; ++nt)
                acc[mt][nt] = __builtin_amdgcn_mfma_f32_16x16x32_bf16(af[mt], bf[nt], acc[mt][nt], 0, 0, 0);
    }
    __syncthreads();   // emb reads done; safe to overlay red arrays

    const float scale = 0.0625f;  // 1/sqrt(256)
    float cm[4];
    #pragma unroll
    for (int nt = 0; nt < 4; ++nt) {
        float m = -1e30f;
        #pragma unroll
        for (int mt = 0; mt < 4; ++mt)
            #pragma unroll
            for (int j = 0; j < 4; ++j) m = fmaxf(m, acc[mt][nt][j]);
        m = fmaxf(m, __shfl_xor(m, 16));
        m = fmaxf(m, __shfl_xor(m, 32));
        cm[nt] = m * scale;
    }
    if (lane < 16) {
        #pragma unroll
        for (int nt = 0; nt < 4; ++nt)
            redm[wmi * 128 + wni * 64 + nt * 16 + lr] = cm[nt];
    }
    __syncthreads();
    float cmax[4];
    #pragma unroll
    for (int nt = 0; nt < 4; ++nt) {
        int c = wni * 64 + nt * 16 + lr;
        cmax[nt] = fmaxf(redm[c], redm[128 + c]);
    }
    float cs[4];
    #pragma unroll
    for (int nt = 0; nt < 4; ++nt) {
        float s = 0.f;
        #pragma unroll
        for (int mt = 0; mt < 4; ++mt)
            #pragma unroll
            for (int j = 0; j < 4; ++j) {
                float p = __expf(acc[mt][nt][j] * scale - cmax[nt]);
                acc[mt][nt][j] = p;
                s += p;
            }
        s += __shfl_xor(s, 16);
        s += __shfl_xor(s, 32);
        cs[nt] = s;
    }
    if (lane < 16) {
        #pragma unroll
        for (int nt = 0; nt < 4; ++nt)
            reds[wmi * 128 + wni * 64 + nt * 16 + lr] = cs[nt];
    }
    __syncthreads();
    #pragma unroll
    for (int nt = 0; nt < 4; ++nt) {
        int c = wni * 64 + nt * 16 + lr;
        float inv = 1.f / (reds[c] + reds[128 + c]);
        int col = t0 + c;
        #pragma unroll
        for (int mt = 0; mt < 4; ++mt)
            #pragma unroll
            for (int j = 0; j < 4; ++j) {
                int row = wmi * 64 + mt * 16 + ko * 4 + j;
                float a = acc[mt][nt][j] * inv;
                size_t idx = ((size_t)(z * 128 + row)) * 1024 + col;
                attnF[idx] = a;
                attnB[idx] = f2bf(a);
            }
    }
}

// ---------------- y = attn @ x4 (per b,g) ----------------
__global__ __launch_bounds__(256) void y_gemm(
    const short* __restrict__ attnB, const short* __restrict__ x4b,
    float* __restrict__ yF, short* __restrict__ yB)
{
    __shared__ short lsA[128 * 40];
    __shared__ short lsB[128 * 40];
    const int tid = threadIdx.x;
    const int z = blockIdx.y;
    const int d0 = blockIdx.x * 128;
    const short* A = attnB + (size_t)z * 131072;
    const short* X = x4b + (size_t)z * 262144 + d0;
    const int lane = tid & 63;
    const int w = tid >> 6;
    const int wmi = w >> 1, wni = w & 1;
    const int lr = lane & 15, ko = lane >> 4;
    const int r0 = tid >> 1, oc0 = (tid * 2) & 3;
    const int rb = tid >> 3, ocb = (tid * 2) & 15;

    const short* Ap = A + (size_t)r0 * 1024 + oc0 * 8;
    const short* Xp = X + (size_t)rb * 256 + ocb * 8;

    s16x8 pa0 = *(const s16x8*)(Ap);
    s16x8 pa1 = *(const s16x8*)(Ap + 8);
    s16x8 pv0 = *(const s16x8*)(Xp);
    s16x8 pv1 = *(const s16x8*)(Xp + 8);

    f32x4 acc[4][4] = {};
    for (int k0 = 0; k0 < 1024; k0 += 32) {
        *(s16x8*)&lsA[r0 * 40 + oc0 * 8]     = pa0;
        *(s16x8*)&lsA[r0 * 40 + oc0 * 8 + 8] = pa1;
        #pragma unroll
        for (int j = 0; j < 8; ++j) {
            int dd = ocb * 8 + j;
            lsB[dd * 40 + ((((rb >> 3) ^ ((dd >> 4) & 3)) << 3) | (rb & 7))] = pv0[j];
            int dd2 = dd + 8;
            lsB[dd2 * 40 + ((((rb >> 3) ^ ((dd2 >> 4) & 3)) << 3) | (rb & 7))] = pv1[j];
        }
        __syncthreads();
        if (k0 + 32 < 1024) {
            pa0 = *(const s16x8*)(Ap + k0 + 32);
            pa1 = *(const s16x8*)(Ap + k0 + 40);
            pv0 = *(const s16x8*)(Xp + (size_t)(k0 + 32) * 256);
            pv1 = *(const s16x8*)(Xp + (size_t)(k0 + 32) * 256 + 8);
        }
        #pragma unroll
        for (int mt = 0; mt < 4; ++mt) {
            s16x8 a = *(const s16x8*)&lsA[(wmi * 64 + mt * 16 + lr) * 40 + ko * 8];
            #pragma unroll
            for (int nt = 0; nt < 4; ++nt) {
                int dd = wni * 64 + nt * 16 + lr;
                s16x8 b = *(const s16x8*)&lsB[dd * 40 + ((ko ^ ((dd >> 4) & 3)) << 3)];
                acc[mt][nt] = __builtin_amdgcn_mfma_f32_16x16x32_bf16(a, b, acc[mt][nt], 0, 0, 0);
            }
        }
        __syncthreads();
    }
    const int cr = ko * 4, cc = lr;
    #pragma unroll
    for (int mt = 0; mt < 4; ++mt)
    #pragma unroll
    for (int nt = 0; nt < 4; ++nt)
        #pragma unroll
        for (int j = 0; j < 4; ++j) {
            int krow = wmi * 64 + mt * 16 + cr + j;
            int col = d0 + wni * 64 + nt * 16 + cc;
            float v = acc[mt][nt][j];
            size_t idx = ((size_t)(z * 128 + krow)) * 256 + col;
            yF[idx] = v;
            yB[idx] = f2bf(v);
        }
}

// ---------------- per-(nb,h) MHA: s2 = qk^T, softmax rows, o = a v ----------------
__global__ __launch_bounds__(256) void mha(
    const short* __restrict__ qkvb, short* __restrict__ ob)
{
    __shared__ short la[128 * 136];   // attn bf16; also overlays lq/lk below
    __shared__ short lvt[32 * 136];   // v transposed [d][s]
    __shared__ float redm[2 * 128];
    __shared__ float reds[2 * 128];
    short* lq = la;                   // [128][40]
    short* lk = la + 128 * 40;        // [128][40]
    const int tid = threadIdx.x;
    const int nb = blockIdx.x >> 3;
    const int h = blockIdx.x & 7;
    const int lane = tid & 63;
    const int w = tid >> 6;
    const int wmi = w >> 1, wni = w & 1;
    const int lr = lane & 15, ko = lane >> 4;
    const int sv = tid >> 1, oc0 = (tid * 2) & 3;
    {
        const short* qp = qkvb + ((size_t)sv * 128 + nb) * 768 + h * 32 + oc0 * 8;
        *(s16x8*)&lq[sv * 40 + oc0 * 8]     = *(const s16x8*)qp;
        *(s16x8*)&lq[sv * 40 + oc0 * 8 + 8] = *(const s16x8*)(qp + 8);
        const short* kp = qp + 256;
        *(s16x8*)&lk[sv * 40 + oc0 * 8]     = *(const s16x8*)kp;
        *(s16x8*)&lk[sv * 40 + oc0 * 8 + 8] = *(const s16x8*)(kp + 8);
        const short* vp = qp + 512;
        s16x8 v0 = *(const s16x8*)vp;
        s16x8 v1 = *(const s16x8*)(vp + 8);
        #pragma unroll
        for (int j = 0; j < 8; ++j) {
            lvt[(oc0 * 8 + j) * 136 + sv]     = v0[j];
            lvt[(oc0 * 8 + 8 + j) * 136 + sv] = v1[j];
        }
    }
    __syncthreads();
    f32x4 acc[4][4] = {};
    #pragma unroll
    for (int mt = 0; mt < 4; ++mt) {
        s16x8 a = *(const s16x8*)&lq[(wmi * 64 + mt * 16 + lr) * 40 + ko * 8];
        #pragma unroll
        for (int nt = 0; nt < 4; ++nt) {
            s16x8 b = *(const s16x8*)&lk[(wni * 64 + nt * 16 + lr) * 40 + ko * 8];
            acc[mt][nt] = __builtin_amdgcn_mfma_f32_16x16x32_bf16(a, b, acc[mt][nt], 0, 0, 0);
        }
    }
    const float scale = 0.1767766953f;  // 1/sqrt(32)
    float rm[4][4];
    #pragma unroll
    for (int mt = 0; mt < 4; ++mt)
        #pragma unroll
        for (int j = 0; j < 4; ++j) {
            float m = -1e30f;
            #pragma unroll
            for (int nt = 0; nt < 4; ++nt) m = fmaxf(m, acc[mt][nt][j]);
            m = fmaxf(m, __shfl_xor(m, 1));
            m = fmaxf(m, __shfl_xor(m, 2));
            m = fmaxf(m, __shfl_xor(m, 4));
            m = fmaxf(m, __shfl_xor(m, 8));
            rm[mt][j] = m * scale;
        }
    if (lr == 0) {
        #pragma unroll
        for (int mt = 0; mt < 4; ++mt)
            #pragma unroll
            for (int j = 0; j < 4; ++j)
                redm[wni * 128 + wmi * 64 + mt * 16 + ko * 4 + j] = rm[mt][j];
    }
    __syncthreads();
    float rs[4][4];
    #pragma unroll
    for (int mt = 0; mt < 4; ++mt)
        #pragma unroll
        for (int j = 0; j < 4; ++j) {
            int row = wmi * 64 + mt * 16 + ko * 4 + j;
            float mx = fmaxf(redm[row], redm[128 + row]);
            float s = 0.f;
            #pragma unroll
            for (int nt = 0; nt < 4; ++nt) {
                float p = __expf(acc[mt][nt][j] * scale - mx);
                acc[mt][nt][j] = p;
                s += p;
            }
            s += __shfl_xor(s, 1);
            s += __shfl_xor(s, 2);
            s += __shfl_xor(s, 4);
            s += __shfl_xor(s, 8);
            rs[mt][j] = s;
        }
    if (lr == 0) {
        #pragma unroll
        for (int mt = 0; mt < 4; ++mt)
            #pragma unroll
            for (int j = 0; j < 4; ++j)
                reds[wni * 128 + wmi * 64 + mt * 16 + ko * 4 + j] = rs[mt][j];
    }
    __syncthreads();
    #pragma unroll
    for (int mt = 0; mt < 4; ++mt)
        #pragma unroll
        for (int j = 0; j < 4; ++j) {
            int row = wmi * 64 + mt * 16 + ko * 4 + j;
            float inv = 1.f / (reds[row] + reds[128 + row]);
            #pragma unroll
            for (int nt = 0; nt < 4; ++nt) {
                int col = wni * 64 + nt * 16 + lr;
                la[row * 136 + col] = f2bf(acc[mt][nt][j] * inv);
            }
        }
    __syncthreads();
    f32x4 acc2[2][2] = {};
    #pragma unroll
    for (int ks = 0; ks < 4; ++ks)
        #pragma unroll
        for (int mt = 0; mt < 2; ++mt) {
            s16x8 a = *(const s16x8*)&la[(w * 32 + mt * 16 + lr) * 136 + ks * 32 + ko * 8];
            #pragma unroll
            for (int nt = 0; nt < 2; ++nt) {
                s16x8 b = *(const s16x8*)&lvt[(nt * 16 + lr) * 136 + ks * 32 + ko * 8];
                acc2[mt][nt] = __builtin_amdgcn_mfma_f32_16x16x32_bf16(a, b, acc2[mt][nt], 0, 0, 0);
            }
        }
    const int cr = ko * 4, cc = lr;
    #pragma unroll
    for (int mt = 0; mt < 2; ++mt)
    #pragma unroll
    for (int nt = 0; nt < 2; ++nt)
        #pragma unroll
        for (int j = 0; j < 4; ++j) {
            int s = w * 32 + mt * 16 + cr + j;
            int d = nt * 16 + cc;
            ob[((size_t)s * 128 + nb) * 256 + h * 32 + d] = f2bf(acc2[mt][nt][j]);
        }
}

// ---------------- residual + layernorm: wave per row, f32x4 ----------------
__global__ __launch_bounds__(256) void ln_res(
    const float* __restrict__ zin, const float* __restrict__ res,
    const float* __restrict__ gw, const float* __restrict__ gb,
    float* __restrict__ outF, short* __restrict__ outB)
{
    const int row = blockIdx.x * 4 + (threadIdx.x >> 6);
    const int lane = threadIdx.x & 63;
    const size_t base = (size_t)row * 256 + lane * 4;
    f32x4 a = *(const f32x4*)(zin + base);
    f32x4 b = *(const f32x4*)(res + base);
    f32x4 v;
    #pragma unroll
    for (int j = 0; j < 4; ++j) v[j] = a[j] + b[j];
    float s1 = v[0] + v[1] + v[2] + v[3];
    float s2 = v[0]*v[0] + v[1]*v[1] + v[2]*v[2] + v[3]*v[3];
    #pragma unroll
    for (int o = 1; o < 64; o <<= 1) {
        s1 += __shfl_xor(s1, o);
        s2 += __shfl_xor(s2, o);
    }
    float m = s1 * 0.00390625f;
    float var = s2 * 0.00390625f - m * m;
    float rstd = rsqrtf(var + 1e-5f);
    f32x4 g = *(const f32x4*)(gw + lane * 4);
    f32x4 bb = *(const f32x4*)(gb + lane * 4);
    f32x4 o; s16x4 obv;
    #pragma unroll
    for (int j = 0; j < 4; ++j) {
        o[j] = (v[j] - m) * rstd * g[j] + bb[j];
        obv[j] = f2bf(o[j]);
    }
    *(f32x4*)(outF + base) = o;
    *(s16x4*)(outB + base) = obv;
}

extern "C" void kernel_launch(void* const* d_in, const int* in_sizes, int n_in,
                              void* d_out, int out_size, void* d_ws, size_t ws_size,
                              hipStream_t stream)
{
    const float* x    = (const float*)d_in[0];
    const float* Wlin = (const float*)d_in[1];
    const float* blin = (const float*)d_in[2];
    const float* emb  = (const float*)d_in[3];
    const float* ipw  = (const float*)d_in[4];
    const float* ipb  = (const float*)d_in[5];
    const float* outw = (const float*)d_in[6];
    const float* outb = (const float*)d_in[7];
    const float* linw = (const float*)d_in[8];
    const float* linb = (const float*)d_in[9];
    const float* ln1w = (const float*)d_in[10];
    const float* ln1b = (const float*)d_in[11];
    const float* ln2w = (const float*)d_in[12];
    const float* ln2b = (const float*)d_in[13];

    char* ws = (char*)d_ws;
    short* x4_b   = (short*)(ws);                       // 67,108,864 B
    short* attn_b = (short*)(ws + 67108864);            // 33,554,432 B
    float* yF     = (float*)(ws + 100663296);           // 16,777,216 B
    short* y_b    = (short*)(ws + 117440512);           //  8,388,608 B
    char*  wb     = ws + 125829120;                     // weights ~2.5 MB
    short* WT_b   = (short*)(wb);
    short* emb_b  = (short*)(wb + 131072);
    short* inw_b  = (short*)(wb + 131072 + 1048576);
    short* outw_b = (short*)(wb + 131072 + 1048576 + 786432);
    short* linw_b = (short*)(wb + 131072 + 1048576 + 786432 + 262144);
    // post-y overlays (x4_b/attn_b dead after y_gemm):
    short* qkv_b  = (short*)(ws);                       // 25,165,824 B
    short* o_b    = (short*)(ws + 25165824);            //  8,388,608 B
    float* op     = (float*)(ws + 33554432);            // 16,777,216 B

    float* out_y    = (float*)d_out;                    // 4,194,304 floats
    float* out_attn = (float*)d_out + 4194304;          // 16,777,216 floats

    castall<<<dim3(1152), dim3(256), 0, stream>>>(emb, ipw, outw, linw,
                                                  emb_b, inw_b, outw_b, linw_b);
    tcast256<<<dim3(256), dim3(256), 0, stream>>>(Wlin, WT_b);

    // x4 = x @ Wlin + b  (M=131072, N=256, K=256), bf16 out
    gemm_rb<true, false, true><<<dim3(1024, 2), dim3(256), 0, stream>>>(
        x, WT_b, blin, nullptr, x4_b, 131072, 256);
    // scores + softmax over latent k; attn -> d_out (f32) + ws (bf16)
    scores_softmax<<<dim3(8, 128), dim3(256), 0, stream>>>(emb_b, x4_b, out_attn, attn_b);
    // y = attn @ x4  -> yF (f32) + y_b (bf16)
    y_gemm<<<dim3(2, 128), dim3(256), 0, stream>>>(attn_b, x4_b, yF, y_b);

    for (int i = 0; i < 2; ++i) {
        gemm_rb<false, false, true><<<dim3(128, 6), dim3(256), 0, stream>>>(
            y_b, inw_b + i * 196608, ipb + i * 768, nullptr, qkv_b, 16384, 768);
        mha<<<dim3(1024), dim3(256), 0, stream>>>(qkv_b, o_b);
        gemm_rb<false, true, false><<<dim3(128, 2), dim3(256), 0, stream>>>(
            o_b, outw_b + i * 65536, outb + i * 256, op, nullptr, 16384, 256);
        ln_res<<<dim3(4096), dim3(256), 0, stream>>>(
            op, yF, ln1w + i * 256, ln1b + i * 256, yF, y_b);
        gemm_rb<false, true, false><<<dim3(128, 2), dim3(256), 0, stream>>>(
            y_b, linw_b + i * 65536, linb + i * 256, op, nullptr, 16384, 256);
        ln_res<<<dim3(4096), dim3(256), 0, stream>>>(
            op, yF, ln2w + i * 256, ln2b + i * 256, (i == 1) ? out_y : yF, y_b);
    }
}

// Round 6
// 521.902 us; speedup vs baseline: 1.1236x; 1.1236x over previous
//
#include <hip/hip_runtime.h>

typedef __attribute__((ext_vector_type(4))) float  f32x4;
typedef __attribute__((ext_vector_type(8))) short  s16x8;
typedef __attribute__((ext_vector_type(4))) short  s16x4;

static __device__ __forceinline__ short f2bf(float f) {
    unsigned int x = __builtin_bit_cast(unsigned int, f);
    x += 0x7fffu + ((x >> 16) & 1u);
    return (short)(x >> 16);
}

// ---------------- prep kernels ----------------
__global__ __launch_bounds__(256) void castall(
    const float* __restrict__ emb, const float* __restrict__ ipw,
    const float* __restrict__ outw, const float* __restrict__ linw,
    short* __restrict__ de, short* __restrict__ di,
    short* __restrict__ dg, short* __restrict__ dl)
{
    int q = blockIdx.x * 256 + threadIdx.x;   // quad index, total 294912
    const float* s; short* d; int o;
    if (q < 131072)      { s = emb;  d = de; o = q; }
    else if (q < 229376) { s = ipw;  d = di; o = q - 131072; }
    else if (q < 262144) { s = outw; d = dg; o = q - 229376; }
    else                 { s = linw; d = dl; o = q - 262144; }
    f32x4 v = *(const f32x4*)(s + (size_t)o * 4);
    s16x4 r;
    #pragma unroll
    for (int j = 0; j < 4; ++j) r[j] = f2bf(v[j]);
    *(s16x4*)(d + (size_t)o * 4) = r;
}

__global__ __launch_bounds__(256) void tcast256(const float* __restrict__ in,
                                                short* __restrict__ out) {
    out[blockIdx.x * 256 + threadIdx.x] = f2bf(in[threadIdx.x * 256 + blockIdx.x]);
}

// ======== 2-phase depth-2 GEMM: C = A * B^T (+bias), BM=128, BK=32 ==========
// Double-buffered LDS (80B padded rows, 2-way-free banks). Reg prefetch issued
// 2 tiles ahead: loads of tile t+2 fly across a full iteration before their
// LDS write. ONE barrier per k-step. NT = n-tiles/wave (BN = NT*32).
template<bool AF32, int NT, bool OF32, bool OB16>
__global__ __launch_bounds__(256) void gemm2p(
    const void* __restrict__ Av, const short* __restrict__ Bm,
    const float* __restrict__ bias,
    float* __restrict__ Cf, short* __restrict__ Cb,
    int M, int N, int K)
{
    constexpr int BN = NT * 32;
    __shared__ short lsA[2][128][40];
    __shared__ short lsB[2][BN][40];
    const int tid = threadIdx.x;
    const int m0 = blockIdx.x * 128;
    const int n0 = blockIdx.y * BN;
    const int lane = tid & 63, w = tid >> 6;
    const int wmi = w >> 1, wni = w & 1;
    const int lr = lane & 15, ko = lane >> 4;
    const int nK = K >> 5;
    const float* Af = (const float*)Av;
    const short* Ah = (const short*)Av;

    f32x4 pf0[4], pf1[4];
    s16x8 pa0[2], pa1[2];
    s16x8 pb0[2], pb1[2];

#define LDA(PF, PA, T) do { const int k0_ = (T) * 32;                               \
    if constexpr (AF32) {                                                           \
        _Pragma("unroll")                                                           \
        for (int i = 0; i < 4; ++i) { int c = i * 256 + tid;                        \
            PF[i] = *(const f32x4*)(Af + (size_t)(m0 + (c >> 3)) * K + k0_ + (c & 7) * 4); } \
    } else {                                                                        \
        _Pragma("unroll")                                                           \
        for (int i = 0; i < 2; ++i) { int c = i * 256 + tid;                        \
            PA[i] = *(const s16x8*)(Ah + (size_t)(m0 + (c >> 2)) * K + k0_ + (c & 3) * 8); } \
    } } while (0)

#define LDB(PB, T) do { const int k0_ = (T) * 32;                                   \
    if constexpr (NT == 4) {                                                        \
        _Pragma("unroll")                                                           \
        for (int i = 0; i < 2; ++i) { int c = i * 256 + tid;                        \
            PB[i] = *(const s16x8*)(Bm + (size_t)(n0 + (c >> 2)) * K + k0_ + (c & 3) * 8); } \
    } else {                                                                        \
        PB[0] = *(const s16x8*)(Bm + (size_t)(n0 + (tid >> 2)) * K + k0_ + (tid & 3) * 8); \
    } } while (0)

#define WR(BUF, PF, PA, PB) do {                                                    \
    if constexpr (AF32) {                                                           \
        _Pragma("unroll")                                                           \
        for (int i = 0; i < 4; ++i) { int c = i * 256 + tid; s16x4 r_;              \
            _Pragma("unroll")                                                       \
            for (int j = 0; j < 4; ++j) r_[j] = f2bf(PF[i][j]);                     \
            *(s16x4*)&lsA[BUF][c >> 3][(c & 7) * 4] = r_; }                         \
    } else {                                                                        \
        _Pragma("unroll")                                                           \
        for (int i = 0; i < 2; ++i) { int c = i * 256 + tid;                        \
            *(s16x8*)&lsA[BUF][c >> 2][(c & 3) * 8] = PA[i]; }                      \
    }                                                                               \
    if constexpr (NT == 4) {                                                        \
        _Pragma("unroll")                                                           \
        for (int i = 0; i < 2; ++i) { int c = i * 256 + tid;                        \
            *(s16x8*)&lsB[BUF][c >> 2][(c & 3) * 8] = PB[i]; }                      \
    } else {                                                                        \
        *(s16x8*)&lsB[BUF][tid >> 2][(tid & 3) * 8] = PB[0];                        \
    } } while (0)

#define MFMA(BUF) do {                                                              \
    s16x8 afr[4], bfr[NT];                                                          \
    _Pragma("unroll")                                                               \
    for (int mt = 0; mt < 4; ++mt)                                                  \
        afr[mt] = *(const s16x8*)&lsA[BUF][wmi * 64 + mt * 16 + lr][ko * 8];        \
    _Pragma("unroll")                                                               \
    for (int nt = 0; nt < NT; ++nt)                                                 \
        bfr[nt] = *(const s16x8*)&lsB[BUF][wni * (NT * 16) + nt * 16 + lr][ko * 8]; \
    _Pragma("unroll")                                                               \
    for (int mt = 0; mt < 4; ++mt)                                                  \
        _Pragma("unroll")                                                           \
        for (int nt = 0; nt < NT; ++nt)                                             \
            acc[mt][nt] = __builtin_amdgcn_mfma_f32_16x16x32_bf16(afr[mt], bfr[nt], acc[mt][nt], 0, 0, 0); \
    } while (0)

    f32x4 acc[4][NT] = {};
    LDA(pf0, pa0, 0); LDB(pb0, 0);
    WR(0, pf0, pa0, pb0);
    LDA(pf0, pa0, 1); LDB(pb0, 1);
    __syncthreads();
    for (int t = 0; t < nK; t += 2) {
        if (t + 2 < nK) { LDA(pf1, pa1, t + 2); LDB(pb1, t + 2); }
        MFMA(0);
        WR(1, pf0, pa0, pb0);             // tile t+1
        __syncthreads();
        if (t + 3 < nK) { LDA(pf0, pa0, t + 3); LDB(pb0, t + 3); }
        MFMA(1);
        if (t + 2 < nK) WR(0, pf1, pa1, pb1);  // tile t+2
        __syncthreads();
    }
#undef LDA
#undef LDB
#undef WR
#undef MFMA
    const int cr = ko * 4, cc = lr;
    #pragma unroll
    for (int mt = 0; mt < 4; ++mt)
    #pragma unroll
    for (int nt = 0; nt < NT; ++nt) {
        const int col = n0 + wni * (NT * 16) + nt * 16 + cc;
        const float bv = bias ? bias[col] : 0.f;
        #pragma unroll
        for (int j = 0; j < 4; ++j) {
            const int row = m0 + wmi * 64 + mt * 16 + cr + j;
            float v = acc[mt][nt][j] + bv;
            size_t idx = (size_t)row * N + col;
            if constexpr (OF32) Cf[idx] = v;
            if constexpr (OB16) Cb[idx] = f2bf(v);
        }
    }
}

// ---------------- scores + softmax over latent k (2-phase depth-2 loop) ------
__global__ __launch_bounds__(256) void scores_softmax(
    const short* __restrict__ embb, const short* __restrict__ x4b,
    float* __restrict__ attnF, short* __restrict__ attnB)
{
    __shared__ short lsA[2][128][40];
    __shared__ short lsB[2][128][40];
    __shared__ float redm[256];
    __shared__ float reds[256];
    const int tid = threadIdx.x;
    const int z = blockIdx.y;
    const int g = z & 15;
    const int t0 = blockIdx.x * 128;
    const short* A = embb + (size_t)g * 32768;
    const short* B = x4b + (size_t)z * 262144 + (size_t)t0 * 256;
    const int lane = tid & 63, w = tid >> 6;
    const int wmi = w >> 1, wni = w & 1;
    const int lr = lane & 15, ko = lane >> 4;

    s16x8 pa0[2], pa1[2], pb0[2], pb1[2];

#define SLD(PA, PB, T) do { const int k0_ = (T) * 32;                               \
    _Pragma("unroll")                                                               \
    for (int i = 0; i < 2; ++i) { int c = i * 256 + tid;                            \
        PA[i] = *(const s16x8*)(A + (size_t)(c >> 2) * 256 + k0_ + (c & 3) * 8);    \
        PB[i] = *(const s16x8*)(B + (size_t)(c >> 2) * 256 + k0_ + (c & 3) * 8); }  \
    } while (0)
#define SWR(BUF, PA, PB) do {                                                       \
    _Pragma("unroll")                                                               \
    for (int i = 0; i < 2; ++i) { int c = i * 256 + tid;                            \
        *(s16x8*)&lsA[BUF][c >> 2][(c & 3) * 8] = PA[i];                            \
        *(s16x8*)&lsB[BUF][c >> 2][(c & 3) * 8] = PB[i]; }                          \
    } while (0)
#define SMFMA(BUF) do {                                                             \
    s16x8 afr[4], bfr[4];                                                           \
    _Pragma("unroll")                                                               \
    for (int mt = 0; mt < 4; ++mt)                                                  \
        afr[mt] = *(const s16x8*)&lsA[BUF][wmi * 64 + mt * 16 + lr][ko * 8];        \
    _Pragma("unroll")                                                               \
    for (int nt = 0; nt < 4; ++nt)                                                  \
        bfr[nt] = *(const s16x8*)&lsB[BUF][wni * 64 + nt * 16 + lr][ko * 8];        \
    _Pragma("unroll")                                                               \
    for (int mt = 0; mt < 4; ++mt)                                                  \
        _Pragma("unroll")                                                           \
        for (int nt = 0; nt < 4; ++nt)                                              \
            acc[mt][nt] = __builtin_amdgcn_mfma_f32_16x16x32_bf16(afr[mt], bfr[nt], acc[mt][nt], 0, 0, 0); \
    } while (0)

    f32x4 acc[4][4] = {};
    SLD(pa0, pb0, 0);
    SWR(0, pa0, pb0);
    SLD(pa0, pb0, 1);
    __syncthreads();
    for (int t = 0; t < 8; t += 2) {
        if (t + 2 < 8) SLD(pa1, pb1, t + 2);
        SMFMA(0);
        SWR(1, pa0, pb0);
        __syncthreads();
        if (t + 3 < 8) SLD(pa0, pb0, t + 3);
        SMFMA(1);
        if (t + 2 < 8) SWR(0, pa1, pb1);
        __syncthreads();
    }
#undef SLD
#undef SWR
#undef SMFMA

    const float scale = 0.0625f;  // 1/sqrt(256)
    float cm[4];
    #pragma unroll
    for (int nt = 0; nt < 4; ++nt) {
        float m = -1e30f;
        #pragma unroll
        for (int mt = 0; mt < 4; ++mt)
            #pragma unroll
            for (int j = 0; j < 4; ++j) m = fmaxf(m, acc[mt][nt][j]);
        m = fmaxf(m, __shfl_xor(m, 16));
        m = fmaxf(m, __shfl_xor(m, 32));
        cm[nt] = m * scale;
    }
    if (lane < 16) {
        #pragma unroll
        for (int nt = 0; nt < 4; ++nt)
            redm[wmi * 128 + wni * 64 + nt * 16 + lr] = cm[nt];
    }
    __syncthreads();
    float cmax[4];
    #pragma unroll
    for (int nt = 0; nt < 4; ++nt) {
        int c = wni * 64 + nt * 16 + lr;
        cmax[nt] = fmaxf(redm[c], redm[128 + c]);
    }
    float cs[4];
    #pragma unroll
    for (int nt = 0; nt < 4; ++nt) {
        float s = 0.f;
        #pragma unroll
        for (int mt = 0; mt < 4; ++mt)
            #pragma unroll
            for (int j = 0; j < 4; ++j) {
                float p = __expf(acc[mt][nt][j] * scale - cmax[nt]);
                acc[mt][nt][j] = p;
                s += p;
            }
        s += __shfl_xor(s, 16);
        s += __shfl_xor(s, 32);
        cs[nt] = s;
    }
    if (lane < 16) {
        #pragma unroll
        for (int nt = 0; nt < 4; ++nt)
            reds[wmi * 128 + wni * 64 + nt * 16 + lr] = cs[nt];
    }
    __syncthreads();
    #pragma unroll
    for (int nt = 0; nt < 4; ++nt) {
        int c = wni * 64 + nt * 16 + lr;
        float inv = 1.f / (reds[c] + reds[128 + c]);
        int col = t0 + c;
        #pragma unroll
        for (int mt = 0; mt < 4; ++mt)
            #pragma unroll
            for (int j = 0; j < 4; ++j) {
                int row = wmi * 64 + mt * 16 + ko * 4 + j;
                float a = acc[mt][nt][j] * inv;
                size_t idx = ((size_t)(z * 128 + row)) * 1024 + col;
                attnF[idx] = a;
                attnB[idx] = f2bf(a);
            }
    }
}

// ---------------- y = attn @ x4, 2-phase depth-2, transpose-staged B ---------
// grid (4 d-blocks of 64, 128 z). A = attn[z] 128x1024 bf16; B = x4^T slice.
__global__ __launch_bounds__(256) void y_gemm(
    const short* __restrict__ attnB, const short* __restrict__ x4b,
    float* __restrict__ yF, short* __restrict__ yB)
{
    __shared__ short lsA[2][128][40];
    __shared__ short lsB[2][64][40];
    const int tid = threadIdx.x;
    const int z = blockIdx.y;
    const int d0 = blockIdx.x * 64;
    const short* A = attnB + (size_t)z * 131072;
    const short* X = x4b + (size_t)z * 262144 + d0;
    const int lane = tid & 63, w = tid >> 6;
    const int wmi = w >> 1, wni = w & 1;
    const int lr = lane & 15, ko = lane >> 4;
    const int kr = tid >> 3, dc = tid & 7;
    const int slot = kr ^ ((tid & 3) << 3);

    s16x8 pa0[2], pa1[2], pb0, pb1;

#define YLD(PA, PB, T) do { const int k0_ = (T) * 32;                               \
    _Pragma("unroll")                                                               \
    for (int i = 0; i < 2; ++i) { int c = i * 256 + tid;                            \
        PA[i] = *(const s16x8*)(A + (size_t)(c >> 2) * 1024 + k0_ + (c & 3) * 8); } \
    PB = *(const s16x8*)(X + (size_t)(k0_ + kr) * 256 + dc * 8);                    \
    } while (0)
#define YWR(BUF, PA, PB) do {                                                       \
    _Pragma("unroll")                                                               \
    for (int i = 0; i < 2; ++i) { int c = i * 256 + tid;                            \
        *(s16x8*)&lsA[BUF][c >> 2][(c & 3) * 8] = PA[i]; }                          \
    _Pragma("unroll")                                                               \
    for (int j = 0; j < 8; ++j) lsB[BUF][dc * 8 + j][slot] = PB[j];                 \
    } while (0)
#define YMFMA(BUF) do {                                                             \
    s16x8 afr[4], bfr[2];                                                           \
    _Pragma("unroll")                                                               \
    for (int mt = 0; mt < 4; ++mt)                                                  \
        afr[mt] = *(const s16x8*)&lsA[BUF][wmi * 64 + mt * 16 + lr][ko * 8];        \
    _Pragma("unroll")                                                               \
    for (int nt = 0; nt < 2; ++nt) { int dd = wni * 32 + nt * 16 + lr;              \
        bfr[nt] = *(const s16x8*)&lsB[BUF][dd][(ko * 8) ^ (((dd >> 3) & 3) << 3)]; }\
    _Pragma("unroll")                                                               \
    for (int mt = 0; mt < 4; ++mt)                                                  \
        _Pragma("unroll")                                                           \
        for (int nt = 0; nt < 2; ++nt)                                              \
            acc[mt][nt] = __builtin_amdgcn_mfma_f32_16x16x32_bf16(afr[mt], bfr[nt], acc[mt][nt], 0, 0, 0); \
    } while (0)

    f32x4 acc[4][2] = {};
    YLD(pa0, pb0, 0);
    YWR(0, pa0, pb0);
    YLD(pa0, pb0, 1);
    __syncthreads();
    for (int t = 0; t < 32; t += 2) {
        if (t + 2 < 32) YLD(pa1, pb1, t + 2);
        YMFMA(0);
        YWR(1, pa0, pb0);
        __syncthreads();
        if (t + 3 < 32) YLD(pa0, pb0, t + 3);
        YMFMA(1);
        if (t + 2 < 32) YWR(0, pa1, pb1);
        __syncthreads();
    }
#undef YLD
#undef YWR
#undef YMFMA
    const int cr = ko * 4, cc = lr;
    #pragma unroll
    for (int mt = 0; mt < 4; ++mt)
    #pragma unroll
    for (int nt = 0; nt < 2; ++nt)
        #pragma unroll
        for (int j = 0; j < 4; ++j) {
            int krow = wmi * 64 + mt * 16 + cr + j;
            int col = d0 + wni * 32 + nt * 16 + cc;
            float v = acc[mt][nt][j];
            size_t idx = ((size_t)(z * 128 + krow)) * 256 + col;
            yF[idx] = v;
            yB[idx] = f2bf(v);
        }
}

// ---------------- per-(nb,h) MHA: s2 = qk^T, softmax rows, o = a v ----------------
__global__ __launch_bounds__(256) void mha(
    const short* __restrict__ qkvb, short* __restrict__ ob)
{
    __shared__ short la[128 * 136];
    __shared__ short lvt[32 * 136];
    __shared__ float redm[2 * 128];
    __shared__ float reds[2 * 128];
    short* lq = la;
    short* lk = la + 128 * 40;
    const int tid = threadIdx.x;
    const int nb = blockIdx.x >> 3;
    const int h = blockIdx.x & 7;
    const int lane = tid & 63;
    const int w = tid >> 6;
    const int wmi = w >> 1, wni = w & 1;
    const int lr = lane & 15, ko = lane >> 4;
    const int sv = tid >> 1, oc0 = (tid * 2) & 3;
    {
        const short* qp = qkvb + ((size_t)sv * 128 + nb) * 768 + h * 32 + oc0 * 8;
        *(s16x8*)&lq[sv * 40 + oc0 * 8]     = *(const s16x8*)qp;
        *(s16x8*)&lq[sv * 40 + oc0 * 8 + 8] = *(const s16x8*)(qp + 8);
        const short* kp = qp + 256;
        *(s16x8*)&lk[sv * 40 + oc0 * 8]     = *(const s16x8*)kp;
        *(s16x8*)&lk[sv * 40 + oc0 * 8 + 8] = *(const s16x8*)(kp + 8);
        const short* vp = qp + 512;
        s16x8 v0 = *(const s16x8*)vp;
        s16x8 v1 = *(const s16x8*)(vp + 8);
        #pragma unroll
        for (int j = 0; j < 8; ++j) {
            lvt[(oc0 * 8 + j) * 136 + sv]     = v0[j];
            lvt[(oc0 * 8 + 8 + j) * 136 + sv] = v1[j];
        }
    }
    __syncthreads();
    f32x4 acc[4][4] = {};
    #pragma unroll
    for (int mt = 0; mt < 4; ++mt) {
        s16x8 a = *(const s16x8*)&lq[(wmi * 64 + mt * 16 + lr) * 40 + ko * 8];
        #pragma unroll
        for (int nt = 0; nt < 4; ++nt) {
            s16x8 b = *(const s16x8*)&lk[(wni * 64 + nt * 16 + lr) * 40 + ko * 8];
            acc[mt][nt] = __builtin_amdgcn_mfma_f32_16x16x32_bf16(a, b, acc[mt][nt], 0, 0, 0);
        }
    }
    const float scale = 0.1767766953f;  // 1/sqrt(32)
    float rm[4][4];
    #pragma unroll
    for (int mt = 0; mt < 4; ++mt)
        #pragma unroll
        for (int j = 0; j < 4; ++j) {
            float m = -1e30f;
            #pragma unroll
            for (int nt = 0; nt < 4; ++nt) m = fmaxf(m, acc[mt][nt][j]);
            m = fmaxf(m, __shfl_xor(m, 1));
            m = fmaxf(m, __shfl_xor(m, 2));
            m = fmaxf(m, __shfl_xor(m, 4));
            m = fmaxf(m, __shfl_xor(m, 8));
            rm[mt][j] = m * scale;
        }
    if (lr == 0) {
        #pragma unroll
        for (int mt = 0; mt < 4; ++mt)
            #pragma unroll
            for (int j = 0; j < 4; ++j)
                redm[wni * 128 + wmi * 64 + mt * 16 + ko * 4 + j] = rm[mt][j];
    }
    __syncthreads();
    float rs[4][4];
    #pragma unroll
    for (int mt = 0; mt < 4; ++mt)
        #pragma unroll
        for (int j = 0; j < 4; ++j) {
            int row = wmi * 64 + mt * 16 + ko * 4 + j;
            float mx = fmaxf(redm[row], redm[128 + row]);
            float s = 0.f;
            #pragma unroll
            for (int nt = 0; nt < 4; ++nt) {
                float p = __expf(acc[mt][nt][j] * scale - mx);
                acc[mt][nt][j] = p;
                s += p;
            }
            s += __shfl_xor(s, 1);
            s += __shfl_xor(s, 2);
            s += __shfl_xor(s, 4);
            s += __shfl_xor(s, 8);
            rs[mt][j] = s;
        }
    if (lr == 0) {
        #pragma unroll
        for (int mt = 0; mt < 4; ++mt)
            #pragma unroll
            for (int j = 0; j < 4; ++j)
                reds[wni * 128 + wmi * 64 + mt * 16 + ko * 4 + j] = rs[mt][j];
    }
    __syncthreads();
    #pragma unroll
    for (int mt = 0; mt < 4; ++mt)
        #pragma unroll
        for (int j = 0; j < 4; ++j) {
            int row = wmi * 64 + mt * 16 + ko * 4 + j;
            float inv = 1.f / (reds[row] + reds[128 + row]);
            #pragma unroll
            for (int nt = 0; nt < 4; ++nt) {
                int col = wni * 64 + nt * 16 + lr;
                la[row * 136 + col] = f2bf(acc[mt][nt][j] * inv);
            }
        }
    __syncthreads();
    f32x4 acc2[2][2] = {};
    #pragma unroll
    for (int ks = 0; ks < 4; ++ks)
        #pragma unroll
        for (int mt = 0; mt < 2; ++mt) {
            s16x8 a = *(const s16x8*)&la[(w * 32 + mt * 16 + lr) * 136 + ks * 32 + ko * 8];
            #pragma unroll
            for (int nt = 0; nt < 2; ++nt) {
                s16x8 b = *(const s16x8*)&lvt[(nt * 16 + lr) * 136 + ks * 32 + ko * 8];
                acc2[mt][nt] = __builtin_amdgcn_mfma_f32_16x16x32_bf16(a, b, acc2[mt][nt], 0, 0, 0);
            }
        }
    const int cr = ko * 4, cc = lr;
    #pragma unroll
    for (int mt = 0; mt < 2; ++mt)
    #pragma unroll
    for (int nt = 0; nt < 2; ++nt)
        #pragma unroll
        for (int j = 0; j < 4; ++j) {
            int s = w * 32 + mt * 16 + cr + j;
            int d = nt * 16 + cc;
            ob[((size_t)s * 128 + nb) * 256 + h * 32 + d] = f2bf(acc2[mt][nt][j]);
        }
}

// ---------------- residual + layernorm: wave per row, f32x4 ----------------
__global__ __launch_bounds__(256) void ln_res(
    const float* __restrict__ zin, const float* __restrict__ res,
    const float* __restrict__ gw, const float* __restrict__ gb,
    float* __restrict__ outF, short* __restrict__ outB)
{
    const int row = blockIdx.x * 4 + (threadIdx.x >> 6);
    const int lane = threadIdx.x & 63;
    const size_t base = (size_t)row * 256 + lane * 4;
    f32x4 a = *(const f32x4*)(zin + base);
    f32x4 b = *(const f32x4*)(res + base);
    f32x4 v;
    #pragma unroll
    for (int j = 0; j < 4; ++j) v[j] = a[j] + b[j];
    float s1 = v[0] + v[1] + v[2] + v[3];
    float s2 = v[0]*v[0] + v[1]*v[1] + v[2]*v[2] + v[3]*v[3];
    #pragma unroll
    for (int o = 1; o < 64; o <<= 1) {
        s1 += __shfl_xor(s1, o);
        s2 += __shfl_xor(s2, o);
    }
    float m = s1 * 0.00390625f;
    float var = s2 * 0.00390625f - m * m;
    float rstd = rsqrtf(var + 1e-5f);
    f32x4 g = *(const f32x4*)(gw + lane * 4);
    f32x4 bb = *(const f32x4*)(gb + lane * 4);
    f32x4 o; s16x4 obv;
    #pragma unroll
    for (int j = 0; j < 4; ++j) {
        o[j] = (v[j] - m) * rstd * g[j] + bb[j];
        obv[j] = f2bf(o[j]);
    }
    *(f32x4*)(outF + base) = o;
    *(s16x4*)(outB + base) = obv;
}

extern "C" void kernel_launch(void* const* d_in, const int* in_sizes, int n_in,
                              void* d_out, int out_size, void* d_ws, size_t ws_size,
                              hipStream_t stream)
{
    const float* x    = (const float*)d_in[0];
    const float* Wlin = (const float*)d_in[1];
    const float* blin = (const float*)d_in[2];
    const float* emb  = (const float*)d_in[3];
    const float* ipw  = (const float*)d_in[4];
    const float* ipb  = (const float*)d_in[5];
    const float* outw = (const float*)d_in[6];
    const float* outb = (const float*)d_in[7];
    const float* linw = (const float*)d_in[8];
    const float* linb = (const float*)d_in[9];
    const float* ln1w = (const float*)d_in[10];
    const float* ln1b = (const float*)d_in[11];
    const float* ln2w = (const float*)d_in[12];
    const float* ln2b = (const float*)d_in[13];

    char* ws = (char*)d_ws;
    short* x4_b   = (short*)(ws);                       // 67,108,864 B
    short* attn_b = (short*)(ws + 67108864);            // 33,554,432 B
    float* yF     = (float*)(ws + 100663296);           // 16,777,216 B
    short* y_b    = (short*)(ws + 117440512);           //  8,388,608 B
    char*  wb     = ws + 125829120;                     // weights ~2.5 MB
    short* WT_b   = (short*)(wb);
    short* emb_b  = (short*)(wb + 131072);
    short* inw_b  = (short*)(wb + 131072 + 1048576);
    short* outw_b = (short*)(wb + 131072 + 1048576 + 786432);
    short* linw_b = (short*)(wb + 131072 + 1048576 + 786432 + 262144);
    short* qkv_b  = (short*)(ws);                       // overlay (x4_b dead)
    short* o_b    = (short*)(ws + 25165824);
    float* op     = (float*)(ws + 33554432);

    float* out_y    = (float*)d_out;
    float* out_attn = (float*)d_out + 4194304;

    castall<<<dim3(1152), dim3(256), 0, stream>>>(emb, ipw, outw, linw,
                                                  emb_b, inw_b, outw_b, linw_b);
    tcast256<<<dim3(256), dim3(256), 0, stream>>>(Wlin, WT_b);

    // x4 = x @ Wlin + b (M=131072, N=256, K=256)
    gemm2p<true, 4, false, true><<<dim3(1024, 2), dim3(256), 0, stream>>>(
        x, WT_b, blin, nullptr, x4_b, 131072, 256, 256);
    scores_softmax<<<dim3(8, 128), dim3(256), 0, stream>>>(emb_b, x4_b, out_attn, attn_b);
    y_gemm<<<dim3(4, 128), dim3(256), 0, stream>>>(attn_b, x4_b, yF, y_b);

    for (int i = 0; i < 2; ++i) {
        gemm2p<false, 2, false, true><<<dim3(128, 12), dim3(256), 0, stream>>>(
            y_b, inw_b + i * 196608, ipb + i * 768, nullptr, qkv_b, 16384, 768, 256);
        mha<<<dim3(1024), dim3(256), 0, stream>>>(qkv_b, o_b);
        gemm2p<false, 2, true, false><<<dim3(128, 4), dim3(256), 0, stream>>>(
            o_b, outw_b + i * 65536, outb + i * 256, op, nullptr, 16384, 256, 256);
        ln_res<<<dim3(4096), dim3(256), 0, stream>>>(
            op, yF, ln1w + i * 256, ln1b + i * 256, yF, y_b);
        gemm2p<false, 2, true, false><<<dim3(128, 4), dim3(256), 0, stream>>>(
            y_b, linw_b + i * 65536, linb + i * 256, op, nullptr, 16384, 256, 256);
        ln_res<<<dim3(4096), dim3(256), 0, stream>>>(
            op, yF, ln2w + i * 256, ln2b + i * 256, (i == 1) ? out_y : yF, y_b);
    }
}